// Round 9
// baseline (86.995 us; speedup 1.0000x reference)
//
#include <hip/hip_runtime.h>

// Output layout (flat f32, reference return order):
//   out0 : (1024,50,3)  @ 0       (153600)
//   steps: (1024,3,49)  @ 153600  (150528)  all 0.01
//   eps  : (1024,3)     @ 304128  (3072)    analytic 0
//   var  : (1024,50,3)  @ 307200  (153600)
//   xi   : (1,10,3)     @ 460800  (30)
#define OUT0_OFF  0
#define STEPS_OFF 153600
#define EPS_OFF   304128
#define VAR_OFF   307200
#define XI_OFF    460800

typedef short bf16x8 __attribute__((ext_vector_type(8)));
typedef float f32x4  __attribute__((ext_vector_type(4)));
typedef unsigned short u16x8 __attribute__((ext_vector_type(8)));

__device__ __forceinline__ unsigned short f2bf(float x) {   // RNE f32->bf16
    union { float f; unsigned u; } c; c.f = x;
    return (unsigned short)((c.u + 0x7FFFu + ((c.u >> 16) & 1u)) >> 16);
}
__device__ __forceinline__ float bf2f(unsigned short h) {
    union { float f; unsigned u; } c; c.u = ((unsigned)h) << 16;
    return c.f;
}

__device__ __forceinline__ void fma16v(const float4& av, const float4& bv,
                                       float acc[4][4]) {
    const float a_[4] = {av.x, av.y, av.z, av.w};
    const float b_[4] = {bv.x, bv.y, bv.z, bv.w};
    #pragma unroll
    for (int i = 0; i < 4; ++i)
        #pragma unroll
        for (int j = 0; j < 4; ++j)
            acc[i][j] = fmaf(a_[i], b_[j], acc[i][j]);
}

// ---------------- GEMM1 + mv1 piggyback ---------------------------------------
// H1 = relu(net_iv(1024x150) @ nW1 + nb1), emitted as bf16 hi/lo split pair.
__global__ __launch_bounds__(128)
void gemm1_k150(const float* __restrict__ A, const float* __restrict__ B,
                const float* __restrict__ bias,
                unsigned short* __restrict__ H1h, unsigned short* __restrict__ H1l,
                const float* __restrict__ px, const float* __restrict__ pW1,
                const float* __restrict__ pb1, float* __restrict__ h1p)
{
    __shared__ __align__(16) float As[150][36];   // transposed A, 21.6 KB
    __shared__ __align__(16) float Bs[150][64];   // 38.4 KB
    const int t = threadIdx.x;

    if (blockIdx.x == 16) {                       // mv1: 32 blocks x 32 j
        float* red = &As[0][0];
        const int jj = t & 31, kg = t >> 5;
        const int j = blockIdx.y * 32 + jj;
        float acc = 0.f;
        for (int k = kg * 16; k < kg * 16 + 16; ++k)
            acc = fmaf(px[k], pW1[k * 1024 + j], acc);
        red[kg * 32 + jj] = acc;
        __syncthreads();
        if (kg == 0) {
            float s = red[jj] + red[32 + jj] + red[64 + jj] + red[96 + jj];
            h1p[j] = fmaxf(s + pb1[j], 0.f);
        }
        return;
    }

    const int col0 = blockIdx.x * 64;
    const int row0 = blockIdx.y * 32;

    for (int i = t; i < 4800; i += 128) {
        const int r = i / 150;
        const int k = i - r * 150;
        As[k][r] = A[row0 * 150 + i];
    }
    {
        const int c4 = (t & 15) * 4;
        for (int k = t >> 4; k < 150; k += 8)
            *(float4*)&Bs[k][c4] = *(const float4*)(B + k * 1024 + col0 + c4);
    }
    __syncthreads();

    const int tx4 = (t & 15) * 4;
    const int ty4 = (t >> 4) * 4;
    float acc[4][4] = {};
    float4 aA = *(const float4*)&As[0][ty4], bA = *(const float4*)&Bs[0][tx4];
    float4 aB = *(const float4*)&As[1][ty4], bB = *(const float4*)&Bs[1][tx4];
    #pragma unroll 5
    for (int k = 0; k < 150; k += 2) {
        float4 aN0 = {}, bN0 = {}, aN1 = {}, bN1 = {};
        if (k + 2 < 150) {
            aN0 = *(const float4*)&As[k + 2][ty4];
            bN0 = *(const float4*)&Bs[k + 2][tx4];
        }
        if (k + 3 < 150) {
            aN1 = *(const float4*)&As[k + 3][ty4];
            bN1 = *(const float4*)&Bs[k + 3][tx4];
        }
        fma16v(aA, bA, acc);
        fma16v(aB, bB, acc);
        aA = aN0; bA = bN0; aB = aN1; bB = bN1;
    }
    #pragma unroll
    for (int i = 0; i < 4; ++i) {
        const int r = row0 + ty4 + i;
        #pragma unroll
        for (int j = 0; j < 4; ++j) {
            const int c = col0 + tx4 + j;
            const float v = fmaxf(acc[i][j] + bias[c], 0.f);
            const unsigned short h = f2bf(v);
            H1h[r * 1024 + c] = h;
            H1l[r * 1024 + c] = f2bf(v - bf2f(h));
        }
    }
}

// ---------------- transp_w2: nW2(1024x1024 [k][n]) -> W2T hi/lo ([n][k] bf16) --
__global__ __launch_bounds__(256)
void transp_w2(const float* __restrict__ w,
               unsigned short* __restrict__ th, unsigned short* __restrict__ tl)
{
    __shared__ float Ts[64][65];
    const int t = threadIdx.x;
    const int n0 = blockIdx.x * 64, k0 = blockIdx.y * 64;
    const int g = t >> 6;         // 0..3
    const int l = t & 63;
    #pragma unroll
    for (int i = 0; i < 16; ++i) {
        const int kl = g * 16 + i;
        Ts[kl][l] = w[(k0 + kl) * 1024 + n0 + l];
    }
    __syncthreads();
    #pragma unroll
    for (int i = 0; i < 16; ++i) {
        const int nl = g * 16 + i;
        const float x = Ts[l][nl];
        const unsigned short h = f2bf(x);
        th[(long)(n0 + nl) * 1024 + k0 + l] = h;
        tl[(long)(n0 + nl) * 1024 + k0 + l] = f2bf(x - bf2f(h));
    }
}

// ---------------- gemm2_mfma: split-bf16 MFMA GEMM, 128x128 tile --------------
// D = Ah*Bh + Ah*Bl + Al*Bh (f32 acc), K-step 32, mfma_f32_16x16x32_bf16.
// A from H1h/H1l [m][k]; B from W2Th/W2Tl [n][k] (pre-transposed).
// 4 waves, each a 64x64 quadrant. Split-K via blockIdx.z; z==SK layer runs mv2.
__global__ __launch_bounds__(256, 1)
void gemm2_mfma(const unsigned short* __restrict__ Ah, const unsigned short* __restrict__ Al,
                const unsigned short* __restrict__ Bh, const unsigned short* __restrict__ Bl,
                float* __restrict__ C, int K, int kchunk, long pstride, int SK,
                const float* __restrict__ mx, const float* __restrict__ mW,
                float* __restrict__ my)
{
    // [buf][mat: Ah,Al,Bh,Bl][kg 4][row 128][8 k] bf16 -> 64 KB
    __shared__ __align__(16) unsigned short L[2][4][4096];
    const int t = threadIdx.x;

    if (blockIdx.z == (unsigned)SK) {             // mv2: 64 blocks x 16 j
        const int idx = blockIdx.y * gridDim.x + blockIdx.x;
        if (idx >= 64) return;
        float* red = (float*)&L[0][0][0];
        const int jj = t & 15, kg = t >> 4;
        const int j = idx * 16 + jj;
        float acc = 0.f;
        const int k0 = kg * 64;
        for (int k = k0; k < k0 + 64; ++k)
            acc = fmaf(mx[k], mW[k * 1024 + j], acc);
        red[kg * 16 + jj] = acc;
        __syncthreads();
        if (kg == 0) {
            float s = 0.f;
            #pragma unroll
            for (int g = 0; g < 16; ++g) s += red[g * 16 + jj];
            my[j] = s;
        }
        return;
    }

    const int n0 = blockIdx.x * 128;
    const int m0 = blockIdx.y * 128;
    const int k0 = blockIdx.z * kchunk;
    const int nk = kchunk >> 5;                   // K-steps of 32

    const int srow = t >> 1, kh = t & 1;          // staging map
    auto stage = [&](int buf, int kt) {
        const long kb = k0 + kt * 32 + kh * 16;
        const u16x8* pah = (const u16x8*)(Ah + (long)(m0 + srow) * K + kb);
        const u16x8* pal = (const u16x8*)(Al + (long)(m0 + srow) * K + kb);
        const u16x8* pbh = (const u16x8*)(Bh + (long)(n0 + srow) * K + kb);
        const u16x8* pbl = (const u16x8*)(Bl + (long)(n0 + srow) * K + kb);
        u16x8 va0 = pah[0], va1 = pah[1];
        u16x8 vl0 = pal[0], vl1 = pal[1];
        u16x8 vb0 = pbh[0], vb1 = pbh[1];
        u16x8 vm0 = pbl[0], vm1 = pbl[1];
        unsigned short* base = &L[buf][0][0];
        const int w0 = (kh * 2) * 1024 + srow * 8;
        const int w1 = (kh * 2 + 1) * 1024 + srow * 8;
        *(u16x8*)(base +  0    + w0) = va0; *(u16x8*)(base +  0    + w1) = va1;
        *(u16x8*)(base + 4096  + w0) = vl0; *(u16x8*)(base + 4096  + w1) = vl1;
        *(u16x8*)(base + 8192  + w0) = vb0; *(u16x8*)(base + 8192  + w1) = vb1;
        *(u16x8*)(base + 12288 + w0) = vm0; *(u16x8*)(base + 12288 + w1) = vm1;
    };

    const int wv = t >> 6;
    const int wm = (wv >> 1) * 64, wn = (wv & 1) * 64;
    const int lane = t & 63;
    const int lr = lane & 15, kg = lane >> 4;

    f32x4 acc[4][4] = {};

    stage(0, 0);
    __syncthreads();
    for (int kt = 0; kt < nk; ++kt) {
        const int buf = kt & 1;
        const short* lb = (const short*)&L[buf][0][0];
        bf16x8 ah[4], al[4], bh[4], bl_[4];
        #pragma unroll
        for (int rt = 0; rt < 4; ++rt) {
            const int ro = kg * 1024 + (wm + rt * 16 + lr) * 8;
            ah[rt] = *(const bf16x8*)(lb + ro);
            al[rt] = *(const bf16x8*)(lb + 4096 + ro);
        }
        #pragma unroll
        for (int ct = 0; ct < 4; ++ct) {
            const int co = kg * 1024 + (wn + ct * 16 + lr) * 8;
            bh[ct]  = *(const bf16x8*)(lb + 8192 + co);
            bl_[ct] = *(const bf16x8*)(lb + 12288 + co);
        }
        if (kt + 1 < nk) stage(buf ^ 1, kt + 1);   // T14: issue before MFMAs
        #pragma unroll
        for (int rt = 0; rt < 4; ++rt)
            #pragma unroll
            for (int ct = 0; ct < 4; ++ct) {
                acc[rt][ct] = __builtin_amdgcn_mfma_f32_16x16x32_bf16(
                                  ah[rt], bh[ct], acc[rt][ct], 0, 0, 0);
                acc[rt][ct] = __builtin_amdgcn_mfma_f32_16x16x32_bf16(
                                  ah[rt], bl_[ct], acc[rt][ct], 0, 0, 0);
                acc[rt][ct] = __builtin_amdgcn_mfma_f32_16x16x32_bf16(
                                  al[rt], bh[ct], acc[rt][ct], 0, 0, 0);
            }
        __syncthreads();
    }

    // C/D layout: row = (lane>>4)*4 + j, col = lane&15  [m89-verified]
    float* Cb = C + (long)blockIdx.z * pstride;
    #pragma unroll
    for (int rt = 0; rt < 4; ++rt)
        #pragma unroll
        for (int ct = 0; ct < 4; ++ct)
            #pragma unroll
            for (int j = 0; j < 4; ++j)
                Cb[(long)(m0 + wm + rt * 16 + kg * 4 + j) * 1024 +
                   (n0 + wn + ct * 16 + lr)] = acc[rt][ct][j];
}

// ---------------- gemm32: 32x64 tile, 4x4 micro, 128 thr, BK=16 dbuf ----------
__global__ __launch_bounds__(128, 1)
void gemm32(const float* __restrict__ A, const float* __restrict__ B,
            float* __restrict__ C, int lda, int N, int kchunk, long pstride)
{
    __shared__ __align__(16) float As[2][16][36];
    __shared__ __align__(16) float Bs[2][16][64];
    const int t = threadIdx.x;
    const int col0 = blockIdx.x * 64;
    const int row0 = blockIdx.y * 32;
    const int k0   = blockIdx.z * kchunk;
    const int nk   = kchunk >> 4;

    const int ar = t >> 2, ak = (t & 3) << 2;
    const int bk = t >> 4, bc = (t & 15) << 2;
    const float* Ap  = A + (long)(row0 + ar) * lda + k0 + ak;
    const float* Bp0 = B + (long)(k0 + bk) * N + col0 + bc;

    float4 ga, gb0, gb1;
    auto loadG = [&](int kt) {
        ga  = *(const float4*)(Ap + kt * 16);
        gb0 = *(const float4*)(Bp0 + (long)kt * 16 * N);
        gb1 = *(const float4*)(Bp0 + ((long)kt * 16 + 8) * N);
    };
    auto writeL = [&](int buf) {
        As[buf][ak + 0][ar] = ga.x;
        As[buf][ak + 1][ar] = ga.y;
        As[buf][ak + 2][ar] = ga.z;
        As[buf][ak + 3][ar] = ga.w;
        *(float4*)&Bs[buf][bk][bc]     = gb0;
        *(float4*)&Bs[buf][bk + 8][bc] = gb1;
    };

    loadG(0);
    writeL(0);
    __syncthreads();

    const int tx4 = (t & 15) << 2;
    const int ty4 = (t >> 4) << 2;
    float acc[4][4] = {};
    for (int kt = 0; kt < nk; ++kt) {
        const int cur = kt & 1;
        if (kt + 1 < nk) loadG(kt + 1);

        float4 aA = *(const float4*)&As[cur][0][ty4];
        float4 bA = *(const float4*)&Bs[cur][0][tx4];
        float4 aB = *(const float4*)&As[cur][1][ty4];
        float4 bB = *(const float4*)&Bs[cur][1][tx4];
        #pragma unroll
        for (int kk = 0; kk < 16; kk += 2) {
            float4 aN0 = {}, bN0 = {}, aN1 = {}, bN1 = {};
            if (kk + 2 < 16) {
                aN0 = *(const float4*)&As[cur][kk + 2][ty4];
                bN0 = *(const float4*)&Bs[cur][kk + 2][tx4];
            }
            if (kk + 3 < 16) {
                aN1 = *(const float4*)&As[cur][kk + 3][ty4];
                bN1 = *(const float4*)&Bs[cur][kk + 3][tx4];
            }
            fma16v(aA, bA, acc);
            fma16v(aB, bB, acc);
            aA = aN0; bA = bN0; aB = aN1; bB = bN1;
        }

        if (kt + 1 < nk) writeL(cur ^ 1);
        __syncthreads();
    }

    float* Cb = C + (long)blockIdx.z * pstride;
    #pragma unroll
    for (int i = 0; i < 4; ++i) {
        const long r = row0 + ty4 + i;
        float4 v = {acc[i][0], acc[i][1], acc[i][2], acc[i][3]};
        *(float4*)&Cb[r * N + col0 + tx4] = v;
    }
}

// ---------------- reduce GEMM2 split-K=4 (+bias+relu) + mv3 piggyback ---------
__global__ __launch_bounds__(256)
void reduce4_mv3(const float* __restrict__ P, const float* __restrict__ bias,
                 float* __restrict__ H2,
                 const float* __restrict__ pvec, const float* __restrict__ pb2,
                 const float* __restrict__ pW3, const float* __restrict__ pb3,
                 const float* __restrict__ mask, float* __restrict__ xi)
{
    const int t = threadIdx.x;
    if (blockIdx.x >= 1024) {                 // mv3: 15 blocks x 2 j
        const int bid = blockIdx.x - 1024;
        const int j = bid * 2 + (t >> 7);
        const int lane = t & 127;
        float acc = 0.f;
        for (int k = lane; k < 1024; k += 128) {
            float h = fmaxf(pvec[k] + pb2[k], 0.f);
            acc = fmaf(h, pW3[k * 30 + j], acc);
        }
        #pragma unroll
        for (int off = 32; off > 0; off >>= 1) acc += __shfl_down(acc, off, 64);
        __shared__ float red[4];
        if ((t & 63) == 0) red[t >> 6] = acc;
        __syncthreads();
        if ((t & 127) == 0)
            xi[j] = (red[t >> 6] + red[(t >> 6) + 1] + pb3[j]) * mask[j];
        return;
    }
    const int i4 = blockIdx.x * 256 + t;
    float4 p = ((const float4*)P)[i4];
    float4 q = ((const float4*)(P + 1048576))[i4];
    float4 r = ((const float4*)(P + 2097152))[i4];
    float4 s = ((const float4*)(P + 3145728))[i4];
    const int c0 = (i4 << 2) & 1023;
    float4 bv = *(const float4*)&bias[c0];
    float4 v;
    v.x = fmaxf(p.x + q.x + r.x + s.x + bv.x, 0.f);
    v.y = fmaxf(p.y + q.y + r.y + s.y + bv.y, 0.f);
    v.z = fmaxf(p.z + q.z + r.z + s.z + bv.z, 0.f);
    v.w = fmaxf(p.w + q.w + r.w + s.w + bv.w, 0.f);
    ((float4*)H2)[i4] = v;
}

// ---------------- pad nW3 (1024x150) -> B3p (1024x192, zero-padded) -----------
__global__ __launch_bounds__(256)
void pad_w3(const float* __restrict__ w, float* __restrict__ o)
{
    const int i = blockIdx.x * 256 + threadIdx.x;   // 196608
    const int k = i / 192, c = i - k * 192;
    o[i] = (c < 150) ? w[k * 150 + c] : 0.f;
}

// ---------------- ode: GEMM3 8-way reduce + basis/rhs/trapezoid, 4 b/block ----
__global__ __launch_bounds__(256)
void ode_kernel(const float* __restrict__ P3, const float* __restrict__ nb3,
                const float* __restrict__ xi, float* __restrict__ varp,
                float* __restrict__ out0, float* __restrict__ steps,
                float* __restrict__ eps)
{
    const int t  = threadIdx.x;
    const int bl = t >> 6;                    // 0..3
    const int b  = blockIdx.x * 4 + bl;
    const int lt = t & 63;
    __shared__ float s_var[4][152];
    __shared__ float s_xi[30];
    __shared__ float s_rhs[4][50][3];
    if (t < 30) s_xi[t] = xi[t];
    for (int i = lt; i < 150; i += 64) {
        float v = nb3[i];
        #pragma unroll
        for (int s = 0; s < 8; ++s) v += P3[s * 196608 + b * 192 + i];
        s_var[bl][i] = v;
        varp[b * 150 + i] = v;
    }
    __syncthreads();
    if (lt < 50) {
        const float v0 = s_var[bl][lt * 3 + 0];
        const float v1 = s_var[bl][lt * 3 + 1];
        const float v2 = s_var[bl][lt * 3 + 2];
        const float bas[10] = {1.f, v0, v1, v2,
                               v0 * v0, v0 * v1, v0 * v2,
                               v1 * v1, v1 * v2, v2 * v2};
        #pragma unroll
        for (int d = 0; d < 3; ++d) {
            float r = 0.f;
            #pragma unroll
            for (int k = 0; k < 10; ++k) r = fmaf(bas[k], s_xi[k * 3 + d], r);
            s_rhs[bl][lt][d] = r;
        }
    }
    __syncthreads();
    if (lt < 3) {
        float x = s_var[bl][lt];              // iv = var[b,0,lt]
        out0[b * 150 + lt] = x;
        for (int n = 1; n < 50; ++n) {
            x = fmaf(0.005f, s_rhs[bl][n - 1][lt] + s_rhs[bl][n][lt], x);
            out0[b * 150 + n * 3 + lt] = x;
        }
        eps[b * 3 + lt] = 0.f;
    }
    for (int i = lt; i < 147; i += 64) steps[b * 147 + i] = 0.01f;
}

extern "C" void kernel_launch(void* const* d_in, const int* in_sizes, int n_in,
                              void* d_out, int out_size, void* d_ws, size_t ws_size,
                              hipStream_t stream)
{
    const float* net_iv   = (const float*)d_in[0];
    const float* param_in = (const float*)d_in[1];
    const float* pW1 = (const float*)d_in[2];
    const float* pb1 = (const float*)d_in[3];
    const float* pW2 = (const float*)d_in[4];
    const float* pb2 = (const float*)d_in[5];
    const float* pW3 = (const float*)d_in[6];
    const float* pb3 = (const float*)d_in[7];
    const float* nW1 = (const float*)d_in[8];
    const float* nb1 = (const float*)d_in[9];
    const float* nW2 = (const float*)d_in[10];
    const float* nb2 = (const float*)d_in[11];
    const float* nW3 = (const float*)d_in[12];
    const float* nb3 = (const float*)d_in[13];
    const float* mask= (const float*)d_in[14];

    float* out = (float*)d_out;
    float* out0p  = out + OUT0_OFF;
    float* stepsp = out + STEPS_OFF;
    float* epsp   = out + EPS_OFF;
    float* varp   = out + VAR_OFF;
    float* xip    = out + XI_OFF;

    // ws layout: bf16 pairs first (2MB each), then f32 buffers. ~35 MB total.
    unsigned short* H1h  = (unsigned short*)d_ws;     // 1024x1024 bf16
    unsigned short* H1l  = H1h + 1048576;
    unsigned short* W2Th = H1l + 1048576;             // [n][k]
    unsigned short* W2Tl = W2Th + 1048576;
    float* P2   = (float*)(W2Tl + 1048576);           // 4 x 1048576 f32
    float* H2   = P2 + 4194304;                       // 1048576
    float* P3   = H2 + 1048576;                       // 8 x 196608
    float* B3p  = P3 + 1572864;                       // 196608
    float* pvec = B3p + 196608;                       // 1024
    float* h1p  = pvec + 1024;                        // 1024

    // prep: transpose+split nW2; pad nW3 (both independent)
    hipLaunchKernelGGL(transp_w2, dim3(16, 16), dim3(256), 0, stream,
                       nW2, W2Th, W2Tl);
    hipLaunchKernelGGL(pad_w3, dim3(768), dim3(256), 0, stream, nW3, B3p);

    // k1: GEMM1 -> H1 hi/lo (+ mv1 piggyback on bx==16)
    hipLaunchKernelGGL(gemm1_k150, dim3(17, 32), dim3(128), 0, stream,
                       net_iv, nW1, nb1, H1h, H1l, param_in, pW1, pb1, h1p);

    // k2: GEMM2 split-bf16 MFMA, 128x128 tile, split-K=4 (+ mv2 on z==4)
    hipLaunchKernelGGL(gemm2_mfma, dim3(8, 8, 5), dim3(256), 0, stream,
                       H1h, H1l, W2Th, W2Tl, P2, 1024, 256, 1048576L, 4,
                       h1p, pW2, pvec);

    // k3: reduce 4 partials + bias + relu -> H2 (+ mv3 piggyback)
    hipLaunchKernelGGL(reduce4_mv3, dim3(1039), dim3(256), 0, stream,
                       P2, nb2, H2, pvec, pb2, pW3, pb3, mask, xip);

    // k4: GEMM3 32x64 tile, split-K=8 -> 768 blocks, nk=8, padded B (N=192)
    hipLaunchKernelGGL(gemm32, dim3(3, 32, 8), dim3(128), 0, stream,
                       H2, B3p, P3, 1024, 192, 128, 196608L);

    // k5: ode (reduce 8 partials + basis/rhs/trapezoid + fills)
    hipLaunchKernelGGL(ode_kernel, dim3(256), dim3(256), 0, stream,
                       P3, nb3, xip, varp, out0p, stepsp, epsp);
}